// Round 4
// baseline (239.027 us; speedup 1.0000x reference)
//
#include <hip/hip_runtime.h>

#define BB 8
#define NN 2048
#define IND 10
#define QK 32

// Kernel 1: q[b][n][qd] = sum_d s[b,n,d]*Wq[qd,d]; k likewise.
// kt permuted for kernel 2's read: attn thread (wave w, lane i) owns cols
//   {512w + 4i + j : j=0..3} and {512w + 256 + 4i + j : j=0..3}.
// kt float4 index: (b*4+w)*4096 + (ev*8+jc)*64 + i, component c (qd=4ev+c).
__global__ __launch_bounds__(256) void qk_kernel(
    const float* __restrict__ s,
    const float* __restrict__ Wq, const float* __restrict__ Wk,
    float* __restrict__ q_ws, float* __restrict__ kt_ws) {
  int t = blockIdx.x * 256 + threadIdx.x;      // 0 .. B*N*QK-1 (exact)
  int b  = t >> 16;                            // N*QK = 65536
  int n  = (t >> 5) & (NN - 1);
  int qd = t & 31;
  const float* srow = s + (size_t)(b * NN + n) * IND;
  float acq = 0.f, ack = 0.f;
#pragma unroll
  for (int d = 0; d < IND; ++d) {
    float sv = srow[d];
    acq = fmaf(sv, Wq[qd * IND + d], acq);
    ack = fmaf(sv, Wk[qd * IND + d], ack);
  }
  q_ws[(size_t)(b * NN + n) * QK + qd] = acq;
  int w  = n >> 9;                 // wave (512 cols each)
  int m  = n & 511;
  int i  = (m & 255) >> 2;         // lane
  int jc = ((m < 256) ? 0 : 4) + (m & 3);
  int ev = qd >> 2, c = qd & 3;
  kt_ws[(((size_t)(b * 4 + w) * 4096) + (ev * 8 + jc) * 64 + i) * 4 + c] = ack;
}

// Kernel 2: one block = (batch, 8 rows), 256 threads. Thread (w,lane) owns
// cols {512w+4*lane+j} and {512w+256+4*lane+j}, j=0..3, for all 8 rows.
// All G loads issued up front; rows 0-5 parked in LDS (same-thread
// write/read, conflict-free), rows 6-7 held in 16 regs. GEMM then runs with
// ~80 free VGPRs so the 64 L2 k-loads pipeline deeply instead of
// serializing (R3's stall).
__global__ __launch_bounds__(256, 3) void attn_kernel(
    const float* __restrict__ G,
    const float* __restrict__ q_ws, const float* __restrict__ kt_ws,
    float* __restrict__ out) {
  const int tid = threadIdx.x;
  const int b = blockIdx.y;
  const int r0 = blockIdx.x * 8;
  const int w = tid >> 6, lane = tid & 63;

  __shared__ float q_lds[8 * 32];
  __shared__ float g_lds[4 * 6 * 512];   // [wave][row 0-5][512]
  __shared__ float red[4][8];

  const float* Gbase = G + ((size_t)b * NN + r0) * NN + 512 * w + 4 * lane;

  // ---- issue ALL G loads now (consumed after GEMM) ----
  float4 gtmp[6][2];   // rows 0-5, transient (parked to LDS below)
#pragma unroll
  for (int r = 0; r < 6; ++r) {
    gtmp[r][0] = *(const float4*)(Gbase + (size_t)r * NN);
    gtmp[r][1] = *(const float4*)(Gbase + (size_t)r * NN + 256);
  }
  float4 gr[2][2];     // rows 6-7, held in registers through the GEMM
#pragma unroll
  for (int r = 0; r < 2; ++r) {
    gr[r][0] = *(const float4*)(Gbase + (size_t)(6 + r) * NN);
    gr[r][1] = *(const float4*)(Gbase + (size_t)(6 + r) * NN + 256);
  }

  // ---- q stage ----
  q_lds[tid] = q_ws[((size_t)b * NN + r0 + (tid >> 5)) * QK + (tid & 31)];

  // ---- park G rows 0-5 in LDS (frees gtmp before GEMM) ----
#pragma unroll
  for (int r = 0; r < 6; ++r) {
    *(float4*)&g_lds[(w * 6 + r) * 512 + 4 * lane]       = gtmp[r][0];
    *(float4*)&g_lds[(w * 6 + r) * 512 + 256 + 4 * lane] = gtmp[r][1];
  }
  __syncthreads();   // q + all G ready (vmcnt drain happens here, once)

  // ---- GEMM: acc[r][j] = q[r0+r] . k[col(w,lane,j)] ----
  float acc[8][8];
#pragma unroll
  for (int r = 0; r < 8; ++r)
#pragma unroll
    for (int j = 0; j < 8; ++j) acc[r][j] = 0.f;

  const float4* kt =
      (const float4*)kt_ws + ((size_t)(b * 4 + w) * 4096) + lane;
#pragma unroll
  for (int ev = 0; ev < 8; ++ev) {
    float4 q4[8];
#pragma unroll
    for (int r = 0; r < 8; ++r)
      q4[r] = *(const float4*)&q_lds[r * 32 + ev * 4];  // broadcast read
#pragma unroll
    for (int j = 0; j < 8; ++j) {
      float4 k4 = kt[(ev * 8 + j) * 64];  // lane-coalesced, L2-resident
#pragma unroll
      for (int r = 0; r < 8; ++r) {
        acc[r][j] = fmaf(q4[r].x, k4.x, acc[r][j]);
        acc[r][j] = fmaf(q4[r].y, k4.y, acc[r][j]);
        acc[r][j] = fmaf(q4[r].z, k4.z, acc[r][j]);
        acc[r][j] = fmaf(q4[r].w, k4.w, acc[r][j]);
      }
    }
  }

  // ---- v = logits^2 * G, per-thread partial row sums ----
  float rsum[8];
#pragma unroll
  for (int r = 0; r < 8; ++r) {
    float gg[8];
    if (r < 6) {
      *(float4*)&gg[0] = *(const float4*)&g_lds[(w * 6 + r) * 512 + 4 * lane];
      *(float4*)&gg[4] =
          *(const float4*)&g_lds[(w * 6 + r) * 512 + 256 + 4 * lane];
    } else {
      *(float4*)&gg[0] = gr[r - 6][0];
      *(float4*)&gg[4] = gr[r - 6][1];
    }
    float sum = 0.f;
#pragma unroll
    for (int j = 0; j < 8; ++j) {
      float v = acc[r][j];
      v = v * v * gg[j];
      acc[r][j] = v;
      sum += v;
    }
    rsum[r] = sum;
  }

  // ---- 64-lane butterfly reduce, then 4-wave LDS reduce ----
#pragma unroll
  for (int r = 0; r < 8; ++r) {
    float v = rsum[r];
#pragma unroll
    for (int off = 32; off >= 1; off >>= 1) v += __shfl_xor(v, off, 64);
    rsum[r] = v;
  }
  if ((tid & 63) == 0) {
#pragma unroll
    for (int r = 0; r < 8; ++r) red[w][r] = rsum[r];
  }
  __syncthreads();

  float inv[8];
#pragma unroll
  for (int r = 0; r < 8; ++r) {
    float total = red[0][r] + red[1][r] + red[2][r] + red[3][r];
    inv[r] = 1.0f / (total + 1e-6f);
  }

  // ---- scale + coalesced store ----
  float* obase = out + ((size_t)b * NN + r0) * NN + 512 * w + 4 * lane;
#pragma unroll
  for (int r = 0; r < 8; ++r) {
    float4 o0, o1;
    o0.x = acc[r][0] * inv[r]; o0.y = acc[r][1] * inv[r];
    o0.z = acc[r][2] * inv[r]; o0.w = acc[r][3] * inv[r];
    o1.x = acc[r][4] * inv[r]; o1.y = acc[r][5] * inv[r];
    o1.z = acc[r][6] * inv[r]; o1.w = acc[r][7] * inv[r];
    *(float4*)(obase + (size_t)r * NN)       = o0;
    *(float4*)(obase + (size_t)r * NN + 256) = o1;
  }
}

extern "C" void kernel_launch(void* const* d_in, const int* in_sizes, int n_in,
                              void* d_out, int out_size, void* d_ws, size_t ws_size,
                              hipStream_t stream) {
  const float* s  = (const float*)d_in[0];
  const float* G  = (const float*)d_in[1];
  const float* Wq = (const float*)d_in[2];
  const float* Wk = (const float*)d_in[3];
  float* out = (float*)d_out;

  float* q_ws  = (float*)d_ws;                       // B*N*QK floats = 2 MB
  float* kt_ws = q_ws + (size_t)BB * NN * QK;        // another 2 MB

  qk_kernel<<<(BB * NN * QK) / 256, 256, 0, stream>>>(s, Wq, Wk, q_ws, kt_ws);

  dim3 grid(NN / 8, BB);
  attn_kernel<<<grid, 256, 0, stream>>>(G, q_ws, kt_ws, out);
}

// Round 5
// 115.783 us; speedup vs baseline: 2.0644x; 2.0644x over previous
//
#include <hip/hip_runtime.h>
#include <stdint.h>

#define BB 8
#define NN 2048
#define IND 10
#define QK 32

// Kernel 1: q[b][n][qd] = sum_d s[b,n,d]*Wq[qd,d]; k likewise.
// kt permuted for kernel 2's read: attn thread (wave w, lane i) owns cols
//   {512w + 4i + j : j=0..3} and {512w + 256 + 4i + j : j=0..3}.
// kt float4 index: (b*4+w)*4096 + (ev*8+jc)*64 + i, component c (qd=4ev+c).
__global__ __launch_bounds__(256) void qk_kernel(
    const float* __restrict__ s,
    const float* __restrict__ Wq, const float* __restrict__ Wk,
    float* __restrict__ q_ws, float* __restrict__ kt_ws) {
  int t = blockIdx.x * 256 + threadIdx.x;      // 0 .. B*N*QK-1 (exact)
  int b  = t >> 16;                            // N*QK = 65536
  int n  = (t >> 5) & (NN - 1);
  int qd = t & 31;
  const float* srow = s + (size_t)(b * NN + n) * IND;
  float acq = 0.f, ack = 0.f;
#pragma unroll
  for (int d = 0; d < IND; ++d) {
    float sv = srow[d];
    acq = fmaf(sv, Wq[qd * IND + d], acq);
    ack = fmaf(sv, Wk[qd * IND + d], ack);
  }
  q_ws[(size_t)(b * NN + n) * QK + qd] = acq;
  int w  = n >> 9;                 // wave (512 cols each)
  int m  = n & 511;
  int i  = (m & 255) >> 2;         // lane
  int jc = ((m < 256) ? 0 : 4) + (m & 3);
  int ev = qd >> 2, c = qd & 3;
  kt_ws[(((size_t)(b * 4 + w) * 4096) + (ev * 8 + jc) * 64 + i) * 4 + c] = ack;
}

// async global->LDS, 16B per lane; dst is wave-uniform base (+ lane*16 by HW)
__device__ __forceinline__ void gload_lds16(const float* src, float* lds_dst) {
  __builtin_amdgcn_global_load_lds(
      reinterpret_cast<const __attribute__((address_space(1))) uint32_t*>(
          reinterpret_cast<uintptr_t>(src)),
      reinterpret_cast<__attribute__((address_space(3))) uint32_t*>(
          reinterpret_cast<uintptr_t>(lds_dst)),
      16, 0, 0);
}

// Kernel 2: one block = (batch, 4 rows), 256 threads. Thread (w,lane) owns
// cols {512w+4*lane+j} and {512w+256+4*lane+j}, j=0..3, for all 4 rows.
// G goes HBM->LDS via global_load_lds (zero VGPR cost, no spill possible),
// wave-private slabs so no barrier is needed before the epilogue reads.
// GEMM uses an explicit 2-deep k double-buffer (static indices only).
__global__ __launch_bounds__(256, 4) void attn_kernel(
    const float* __restrict__ G,
    const float* __restrict__ q_ws, const float* __restrict__ kt_ws,
    float* __restrict__ out) {
  const int tid = threadIdx.x;
  const int b = blockIdx.y;
  const int r0 = blockIdx.x * 4;
  const int w = tid >> 6, lane = tid & 63;

  __shared__ float g_lds[4][2048];   // 32 KB, wave w owns cols [512w,512w+512)
  __shared__ float q_lds[4][128];    // per-wave private copy of the q tile
  __shared__ float red[4][4];

  // ---- wave-private q copy (rows r0..r0+3 are 128 contiguous floats) ----
  {
    const float* qb = q_ws + ((size_t)b * NN + r0) * QK;
    *(float2*)&q_lds[w][2 * lane] = *(const float2*)&qb[2 * lane];
  }

  // ---- issue G -> LDS (async, zero registers), wave-private slab ----
  {
    const float* gb = G + ((size_t)b * NN + r0) * NN + 512 * w + 4 * lane;
#pragma unroll
    for (int r = 0; r < 4; ++r) {
#pragma unroll
      for (int c = 0; c < 2; ++c) {
        gload_lds16(gb + (size_t)r * NN + 256 * c,
                    &g_lds[r][512 * w + 256 * c]);
      }
    }
  }
  __builtin_amdgcn_sched_barrier(0);  // G loads stay ahead of k loads

  // ---- GEMM: acc[r][j] = q[r0+r] . k[col(w,lane,j)] ----
  float acc[4][8];
#pragma unroll
  for (int r = 0; r < 4; ++r)
#pragma unroll
    for (int j = 0; j < 8; ++j) acc[r][j] = 0.f;

  const float4* kt =
      (const float4*)kt_ws + (size_t)(b * 4 + w) * 4096 + lane;

  float4 ka[8], kb[8];
#pragma unroll
  for (int j = 0; j < 8; ++j) ka[j] = kt[j * 64];  // ev=0

#pragma unroll
  for (int ev = 0; ev < 8; ++ev) {
    if (ev < 7) {
#pragma unroll
      for (int j = 0; j < 8; ++j) kb[j] = kt[((ev + 1) * 8 + j) * 64];
    }
    float q4[4][4];
#pragma unroll
    for (int r = 0; r < 4; ++r)
      *(float4*)q4[r] = *(const float4*)&q_lds[w][r * 32 + ev * 4];
#pragma unroll
    for (int j = 0; j < 8; ++j) {
#pragma unroll
      for (int r = 0; r < 4; ++r) {
        acc[r][j] = fmaf(q4[r][0], ka[j].x, acc[r][j]);
        acc[r][j] = fmaf(q4[r][1], ka[j].y, acc[r][j]);
        acc[r][j] = fmaf(q4[r][2], ka[j].z, acc[r][j]);
        acc[r][j] = fmaf(q4[r][3], ka[j].w, acc[r][j]);
      }
    }
#pragma unroll
    for (int j = 0; j < 8; ++j) ka[j] = kb[j];  // renamed away by unroll
  }

  // ---- wait for G in LDS, then v = logits^2 * G and row partials ----
  asm volatile("s_waitcnt vmcnt(0)" ::: "memory");
  __builtin_amdgcn_sched_barrier(0);

  float rsum[4];
#pragma unroll
  for (int r = 0; r < 4; ++r) {
    float gg[8];
    *(float4*)&gg[0] = *(const float4*)&g_lds[r][512 * w + 4 * lane];
    *(float4*)&gg[4] = *(const float4*)&g_lds[r][512 * w + 256 + 4 * lane];
    float sum = 0.f;
#pragma unroll
    for (int j = 0; j < 8; ++j) {
      float v = acc[r][j];
      v = v * v * gg[j];
      acc[r][j] = v;
      sum += v;
    }
    rsum[r] = sum;
  }

  // ---- 64-lane butterfly reduce, then 4-wave LDS reduce ----
#pragma unroll
  for (int r = 0; r < 4; ++r) {
    float v = rsum[r];
#pragma unroll
    for (int off = 32; off >= 1; off >>= 1) v += __shfl_xor(v, off, 64);
    rsum[r] = v;
  }
  if ((tid & 63) == 0) {
#pragma unroll
    for (int r = 0; r < 4; ++r) red[w][r] = rsum[r];
  }
  __syncthreads();

  float inv[4];
#pragma unroll
  for (int r = 0; r < 4; ++r) {
    float total = red[0][r] + red[1][r] + red[2][r] + red[3][r];
    inv[r] = 1.0f / (total + 1e-6f);
  }

  // ---- scale + coalesced store ----
  float* ob = out + ((size_t)b * NN + r0) * NN + 512 * w + 4 * lane;
#pragma unroll
  for (int r = 0; r < 4; ++r) {
    float4 o0, o1;
    o0.x = acc[r][0] * inv[r]; o0.y = acc[r][1] * inv[r];
    o0.z = acc[r][2] * inv[r]; o0.w = acc[r][3] * inv[r];
    o1.x = acc[r][4] * inv[r]; o1.y = acc[r][5] * inv[r];
    o1.z = acc[r][6] * inv[r]; o1.w = acc[r][7] * inv[r];
    *(float4*)(ob + (size_t)r * NN)       = o0;
    *(float4*)(ob + (size_t)r * NN + 256) = o1;
  }
}

extern "C" void kernel_launch(void* const* d_in, const int* in_sizes, int n_in,
                              void* d_out, int out_size, void* d_ws, size_t ws_size,
                              hipStream_t stream) {
  const float* s  = (const float*)d_in[0];
  const float* G  = (const float*)d_in[1];
  const float* Wq = (const float*)d_in[2];
  const float* Wk = (const float*)d_in[3];
  float* out = (float*)d_out;

  float* q_ws  = (float*)d_ws;                       // B*N*QK floats = 2 MB
  float* kt_ws = q_ws + (size_t)BB * NN * QK;        // another 2 MB

  qk_kernel<<<(BB * NN * QK) / 256, 256, 0, stream>>>(s, Wq, Wk, q_ws, kt_ws);

  dim3 grid(NN / 4, BB);
  attn_kernel<<<grid, 256, 0, stream>>>(G, q_ws, kt_ws, out);
}

// Round 6
// 96.753 us; speedup vs baseline: 2.4705x; 1.1967x over previous
//
#include <hip/hip_runtime.h>
#include <stdint.h>

#define BB 8
#define NN 2048
#define IND 10
#define QK 32

// Kernel 1: q[b][n][qd] = sum_d s[b,n,d]*Wq[qd,d]; k likewise.
// kt permuted for kernel 2's read: attn thread (wave w, lane i) owns cols
//   {512w + 4i + j : j=0..3} and {512w + 256 + 4i + j : j=0..3}.
// kt float4 index: (b*4+w)*4096 + (ev*8+jc)*64 + i, component c (qd=4ev+c).
__global__ __launch_bounds__(256) void qk_kernel(
    const float* __restrict__ s,
    const float* __restrict__ Wq, const float* __restrict__ Wk,
    float* __restrict__ q_ws, float* __restrict__ kt_ws) {
  int t = blockIdx.x * 256 + threadIdx.x;      // 0 .. B*N*QK-1 (exact)
  int b  = t >> 16;                            // N*QK = 65536
  int n  = (t >> 5) & (NN - 1);
  int qd = t & 31;
  const float* srow = s + (size_t)(b * NN + n) * IND;
  float acq = 0.f, ack = 0.f;
#pragma unroll
  for (int d = 0; d < IND; ++d) {
    float sv = srow[d];
    acq = fmaf(sv, Wq[qd * IND + d], acq);
    ack = fmaf(sv, Wk[qd * IND + d], ack);
  }
  q_ws[(size_t)(b * NN + n) * QK + qd] = acq;
  int w  = n >> 9;                 // wave (512 cols each)
  int m  = n & 511;
  int i  = (m & 255) >> 2;         // lane
  int jc = ((m < 256) ? 0 : 4) + (m & 3);
  int ev = qd >> 2, c = qd & 3;
  kt_ws[(((size_t)(b * 4 + w) * 4096) + (ev * 8 + jc) * 64 + i) * 4 + c] = ack;
}

// async global->LDS: lane's 16B from per-lane src -> uniform LDS base + lane*16
__device__ __forceinline__ void gload_lds16(const float* src, float* lds_dst) {
  __builtin_amdgcn_global_load_lds(
      reinterpret_cast<const __attribute__((address_space(1))) uint32_t*>(
          reinterpret_cast<uintptr_t>(src)),
      reinterpret_cast<__attribute__((address_space(3))) uint32_t*>(
          reinterpret_cast<uintptr_t>(lds_dst)),
      16, 0, 0);
}

// Kernel 2: one block = (batch, 8 rows), 256 threads. Thread (w,lane) owns
// cols {512w+4*lane+j} and {512w+256+4*lane+j}, j=0..3, for all 8 rows.
// G staged HBM->LDS via global_load_lds into wave-private slabs (zero VGPR,
// no spill possible, no barrier needed: same-wave producer/consumer).
// k: explicit 2-deep double-buffer; issued BEFORE the G loads so the first
// ka consume waits only on ka. No launch_bounds min -> no forced spill.
__global__ __launch_bounds__(256) void attn_kernel(
    const float* __restrict__ G,
    const float* __restrict__ q_ws, const float* __restrict__ kt_ws,
    float* __restrict__ out) {
  const int tid = threadIdx.x;
  const int b = blockIdx.y;
  const int r0 = blockIdx.x * 8;
  const int w = tid >> 6, lane = tid & 63;

  __shared__ float g_lds[4][8][512];  // 64 KB, wave-private col slabs
  __shared__ float q_lds[4][256];     // 4 KB, wave-private q tile copies
  __shared__ float red[4][8];

  // ---- wave-private q copy (8 rows x 32 = 256 contiguous floats) ----
  {
    const float* qb = q_ws + ((size_t)b * NN + r0) * QK;
    *(float4*)&q_lds[w][4 * lane] = *(const float4*)&qb[4 * lane];
  }

  const float4* kt =
      (const float4*)kt_ws + (size_t)(b * 4 + w) * 4096 + lane;

  // ---- k dbuf prologue (oldest in vmcnt queue -> consumed first) ----
  float4 ka[8], kb[8];
#pragma unroll
  for (int j = 0; j < 8; ++j) ka[j] = kt[j * 64];  // ev=0

  // ---- issue G -> LDS (async, zero registers), wave-private slab ----
  {
    const float* gb = G + ((size_t)b * NN + r0) * NN + 512 * w + 4 * lane;
#pragma unroll
    for (int r = 0; r < 8; ++r) {
#pragma unroll
      for (int c = 0; c < 2; ++c)
        gload_lds16(gb + (size_t)r * NN + 256 * c, &g_lds[w][r][256 * c]);
    }
  }

  // ---- GEMM: acc[r][j] = q[r0+r] . k[col(w,lane,j)] ----
  float acc[8][8];
#pragma unroll
  for (int r = 0; r < 8; ++r)
#pragma unroll
    for (int j = 0; j < 8; ++j) acc[r][j] = 0.f;

#pragma unroll
  for (int ev = 0; ev < 8; ++ev) {
    if (ev < 7) {
#pragma unroll
      for (int j = 0; j < 8; ++j) kb[j] = kt[((ev + 1) * 8 + j) * 64];
    }
    float q4[8][4];
#pragma unroll
    for (int r = 0; r < 8; ++r)
      *(float4*)q4[r] = *(const float4*)&q_lds[w][r * 32 + ev * 4];
#pragma unroll
    for (int j = 0; j < 8; ++j) {
#pragma unroll
      for (int r = 0; r < 8; ++r) {
        acc[r][j] = fmaf(q4[r][0], ka[j].x, acc[r][j]);
        acc[r][j] = fmaf(q4[r][1], ka[j].y, acc[r][j]);
        acc[r][j] = fmaf(q4[r][2], ka[j].z, acc[r][j]);
        acc[r][j] = fmaf(q4[r][3], ka[j].w, acc[r][j]);
      }
    }
#pragma unroll
    for (int j = 0; j < 8; ++j) ka[j] = kb[j];  // renamed away by unroll
  }

  // ---- wait for G in LDS (same-wave), then v = s^2 * G + row partials ----
  asm volatile("s_waitcnt vmcnt(0)" ::: "memory");
  __builtin_amdgcn_sched_barrier(0);

  float rsum[8];
#pragma unroll
  for (int r = 0; r < 8; ++r) {
    float gg[8];
    *(float4*)&gg[0] = *(const float4*)&g_lds[w][r][4 * lane];
    *(float4*)&gg[4] = *(const float4*)&g_lds[w][r][256 + 4 * lane];
    float sum = 0.f;
#pragma unroll
    for (int j = 0; j < 8; ++j) {
      float v = acc[r][j];
      v = v * v * gg[j];
      acc[r][j] = v;
      sum += v;
    }
    rsum[r] = sum;
  }

  // ---- 64-lane butterfly reduce, then 4-wave LDS reduce ----
#pragma unroll
  for (int r = 0; r < 8; ++r) {
    float v = rsum[r];
#pragma unroll
    for (int off = 32; off >= 1; off >>= 1) v += __shfl_xor(v, off, 64);
    rsum[r] = v;
  }
  if ((tid & 63) == 0) {
#pragma unroll
    for (int r = 0; r < 8; ++r) red[w][r] = rsum[r];
  }
  __syncthreads();

  float inv[8];
#pragma unroll
  for (int r = 0; r < 8; ++r) {
    float total = red[0][r] + red[1][r] + red[2][r] + red[3][r];
    inv[r] = 1.0f / (total + 1e-6f);
  }

  // ---- scale + coalesced store ----
  float* ob = out + ((size_t)b * NN + r0) * NN + 512 * w + 4 * lane;
#pragma unroll
  for (int r = 0; r < 8; ++r) {
    float4 o0, o1;
    o0.x = acc[r][0] * inv[r]; o0.y = acc[r][1] * inv[r];
    o0.z = acc[r][2] * inv[r]; o0.w = acc[r][3] * inv[r];
    o1.x = acc[r][4] * inv[r]; o1.y = acc[r][5] * inv[r];
    o1.z = acc[r][6] * inv[r]; o1.w = acc[r][7] * inv[r];
    *(float4*)(ob + (size_t)r * NN)       = o0;
    *(float4*)(ob + (size_t)r * NN + 256) = o1;
  }
}

extern "C" void kernel_launch(void* const* d_in, const int* in_sizes, int n_in,
                              void* d_out, int out_size, void* d_ws, size_t ws_size,
                              hipStream_t stream) {
  const float* s  = (const float*)d_in[0];
  const float* G  = (const float*)d_in[1];
  const float* Wq = (const float*)d_in[2];
  const float* Wk = (const float*)d_in[3];
  float* out = (float*)d_out;

  float* q_ws  = (float*)d_ws;                       // B*N*QK floats = 2 MB
  float* kt_ws = q_ws + (size_t)BB * NN * QK;        // another 2 MB

  qk_kernel<<<(BB * NN * QK) / 256, 256, 0, stream>>>(s, Wq, Wk, q_ws, kt_ws);

  dim3 grid(NN / 8, BB);
  attn_kernel<<<grid, 256, 0, stream>>>(G, q_ws, kt_ws, out);
}

// Round 7
// 94.181 us; speedup vs baseline: 2.5379x; 1.0273x over previous
//
#include <hip/hip_runtime.h>
#include <stdint.h>

#define BB 8
#define NN 2048
#define IND 10
#define QK 32

// Kernel 1: q[b][n][qd] = sum_d s[b,n,d]*Wq[qd,d]; k likewise.
// kt permuted for kernel 2's read: attn thread (wave w, lane i) owns cols
//   {512w + 4i + j : j=0..3} and {512w + 256 + 4i + j : j=0..3}.
// kt float4 index: (b*4+w)*4096 + (ev*8+jc)*64 + i, component c (qd=4ev+c).
__global__ __launch_bounds__(256) void qk_kernel(
    const float* __restrict__ s,
    const float* __restrict__ Wq, const float* __restrict__ Wk,
    float* __restrict__ q_ws, float* __restrict__ kt_ws) {
  int t = blockIdx.x * 256 + threadIdx.x;      // 0 .. B*N*QK-1 (exact)
  int b  = t >> 16;                            // N*QK = 65536
  int n  = (t >> 5) & (NN - 1);
  int qd = t & 31;
  const float* srow = s + (size_t)(b * NN + n) * IND;
  float acq = 0.f, ack = 0.f;
#pragma unroll
  for (int d = 0; d < IND; ++d) {
    float sv = srow[d];
    acq = fmaf(sv, Wq[qd * IND + d], acq);
    ack = fmaf(sv, Wk[qd * IND + d], ack);
  }
  q_ws[(size_t)(b * NN + n) * QK + qd] = acq;
  int w  = n >> 9;                 // wave (512 cols each)
  int m  = n & 511;
  int i  = (m & 255) >> 2;         // lane
  int jc = ((m < 256) ? 0 : 4) + (m & 3);
  int ev = qd >> 2, c = qd & 3;
  kt_ws[(((size_t)(b * 4 + w) * 4096) + (ev * 8 + jc) * 64 + i) * 4 + c] = ack;
}

// async global->LDS: lane's 16B from per-lane src -> uniform LDS base + lane*16
__device__ __forceinline__ void gload_lds16(const float* src, float* lds_dst) {
  __builtin_amdgcn_global_load_lds(
      reinterpret_cast<const __attribute__((address_space(1))) uint32_t*>(
          reinterpret_cast<uintptr_t>(src)),
      reinterpret_cast<__attribute__((address_space(3))) uint32_t*>(
          reinterpret_cast<uintptr_t>(lds_dst)),
      16, 0, 0);
}

// Kernel 2: one block = (batch, 8 rows), 256 threads. Thread (w,lane) owns
// cols {512w+4*lane+j} and {512w+256+4*lane+j}, j=0..3, for all 8 rows.
// G staged HBM->LDS in TWO 4-row halves (16 KB each) so total LDS is ~37 KB
// (R6's 70 KB slab capped residency at 1 block/CU -> 11% occupancy).
// Half 0 hides under the GEMM; half 1's latency hides under half-0 epilogue.
// Wave-private slabs: no barriers before the cross-wave reduce.
__global__ __launch_bounds__(256, 3) void attn_kernel(
    const float* __restrict__ G,
    const float* __restrict__ q_ws, const float* __restrict__ kt_ws,
    float* __restrict__ out) {
  const int tid = threadIdx.x;
  const int b = blockIdx.y;
  const int r0 = blockIdx.x * 8;
  const int w = tid >> 6, lane = tid & 63;

  __shared__ float g_lds[4][2][4][512];  // 32 KB: wave, half, row, col
  __shared__ float q_lds[4][256];        // 4 KB, wave-private q tile copies
  __shared__ float red[4][8];

  // ---- wave-private q copy (8 rows x 32 = 256 contiguous floats) ----
  {
    const float* qb = q_ws + ((size_t)b * NN + r0) * QK;
    *(float4*)&q_lds[w][4 * lane] = *(const float4*)&qb[4 * lane];
  }

  const float4* kt =
      (const float4*)kt_ws + (size_t)(b * 4 + w) * 4096 + lane;

  // ---- k dbuf prologue (issued BEFORE G so first k-wait skips G) ----
  float4 ka[8], kb[8];
#pragma unroll
  for (int j = 0; j < 8; ++j) ka[j] = kt[j * 64];  // ev=0

  // ---- issue G rows 0-3 -> LDS half 0 (async, zero registers) ----
  const float* gb = G + ((size_t)b * NN + r0) * NN + 512 * w + 4 * lane;
#pragma unroll
  for (int r = 0; r < 4; ++r) {
#pragma unroll
    for (int c = 0; c < 2; ++c)
      gload_lds16(gb + (size_t)r * NN + 256 * c, &g_lds[w][0][r][256 * c]);
  }

  // ---- GEMM: acc[r][j] = q[r0+r] . k[col(w,lane,j)] ----
  float acc[8][8];
#pragma unroll
  for (int r = 0; r < 8; ++r)
#pragma unroll
    for (int j = 0; j < 8; ++j) acc[r][j] = 0.f;

#pragma unroll
  for (int ev = 0; ev < 8; ++ev) {
    if (ev < 7) {
#pragma unroll
      for (int j = 0; j < 8; ++j) kb[j] = kt[((ev + 1) * 8 + j) * 64];
    }
    float q4[8][4];
#pragma unroll
    for (int r = 0; r < 8; ++r)
      *(float4*)q4[r] = *(const float4*)&q_lds[w][r * 32 + ev * 4];
#pragma unroll
    for (int j = 0; j < 8; ++j) {
#pragma unroll
      for (int r = 0; r < 8; ++r) {
        acc[r][j] = fmaf(q4[r][0], ka[j].x, acc[r][j]);
        acc[r][j] = fmaf(q4[r][1], ka[j].y, acc[r][j]);
        acc[r][j] = fmaf(q4[r][2], ka[j].z, acc[r][j]);
        acc[r][j] = fmaf(q4[r][3], ka[j].w, acc[r][j]);
      }
    }
#pragma unroll
    for (int j = 0; j < 8; ++j) ka[j] = kb[j];  // renamed away by unroll
  }

  // ---- issue G rows 4-7 -> LDS half 1, then process half 0 ----
#pragma unroll
  for (int r = 0; r < 4; ++r) {
#pragma unroll
    for (int c = 0; c < 2; ++c)
      gload_lds16(gb + (size_t)(4 + r) * NN + 256 * c,
                  &g_lds[w][1][r][256 * c]);
  }
  // outstanding <= 8 (the half-1 loads)  =>  half 0 + all k retired
  asm volatile("s_waitcnt vmcnt(8)" ::: "memory");
  __builtin_amdgcn_sched_barrier(0);

  float rsum[8];
#pragma unroll
  for (int r = 0; r < 4; ++r) {
    float gg[8];
    *(float4*)&gg[0] = *(const float4*)&g_lds[w][0][r][4 * lane];
    *(float4*)&gg[4] = *(const float4*)&g_lds[w][0][r][256 + 4 * lane];
    float sum = 0.f;
#pragma unroll
    for (int j = 0; j < 8; ++j) {
      float v = acc[r][j];
      v = v * v * gg[j];
      acc[r][j] = v;
      sum += v;
    }
#pragma unroll
    for (int off = 32; off >= 1; off >>= 1) sum += __shfl_xor(sum, off, 64);
    rsum[r] = sum;   // butterflies here help cover half-1 HBM latency
  }

  asm volatile("s_waitcnt vmcnt(0)" ::: "memory");  // half 1 landed
  __builtin_amdgcn_sched_barrier(0);

#pragma unroll
  for (int r = 4; r < 8; ++r) {
    float gg[8];
    *(float4*)&gg[0] = *(const float4*)&g_lds[w][1][r - 4][4 * lane];
    *(float4*)&gg[4] = *(const float4*)&g_lds[w][1][r - 4][256 + 4 * lane];
    float sum = 0.f;
#pragma unroll
    for (int j = 0; j < 8; ++j) {
      float v = acc[r][j];
      v = v * v * gg[j];
      acc[r][j] = v;
      sum += v;
    }
#pragma unroll
    for (int off = 32; off >= 1; off >>= 1) sum += __shfl_xor(sum, off, 64);
    rsum[r] = sum;
  }

  if ((tid & 63) == 0) {
#pragma unroll
    for (int r = 0; r < 8; ++r) red[w][r] = rsum[r];
  }
  __syncthreads();

  float inv[8];
#pragma unroll
  for (int r = 0; r < 8; ++r) {
    float total = red[0][r] + red[1][r] + red[2][r] + red[3][r];
    inv[r] = 1.0f / (total + 1e-6f);
  }

  // ---- scale + coalesced store ----
  float* ob = out + ((size_t)b * NN + r0) * NN + 512 * w + 4 * lane;
#pragma unroll
  for (int r = 0; r < 8; ++r) {
    float4 o0, o1;
    o0.x = acc[r][0] * inv[r]; o0.y = acc[r][1] * inv[r];
    o0.z = acc[r][2] * inv[r]; o0.w = acc[r][3] * inv[r];
    o1.x = acc[r][4] * inv[r]; o1.y = acc[r][5] * inv[r];
    o1.z = acc[r][6] * inv[r]; o1.w = acc[r][7] * inv[r];
    *(float4*)(ob + (size_t)r * NN)       = o0;
    *(float4*)(ob + (size_t)r * NN + 256) = o1;
  }
}

extern "C" void kernel_launch(void* const* d_in, const int* in_sizes, int n_in,
                              void* d_out, int out_size, void* d_ws, size_t ws_size,
                              hipStream_t stream) {
  const float* s  = (const float*)d_in[0];
  const float* G  = (const float*)d_in[1];
  const float* Wq = (const float*)d_in[2];
  const float* Wk = (const float*)d_in[3];
  float* out = (float*)d_out;

  float* q_ws  = (float*)d_ws;                       // B*N*QK floats = 2 MB
  float* kt_ws = q_ws + (size_t)BB * NN * QK;        // another 2 MB

  qk_kernel<<<(BB * NN * QK) / 256, 256, 0, stream>>>(s, Wq, Wk, q_ws, kt_ws);

  dim3 grid(NN / 8, BB);
  attn_kernel<<<grid, 256, 0, stream>>>(G, q_ws, kt_ws, out);
}